// Round 4
// baseline (196.013 us; speedup 1.0000x reference)
//
#include <hip/hip_runtime.h>
#include <hip/hip_bf16.h>

#define BH 64
#define NKV 8192
#define NQ 2048
#define DIM 128
#define EPSV 1e-6f

typedef __attribute__((ext_vector_type(8))) short bf16x8;
typedef __attribute__((ext_vector_type(4))) float f32x4;

__device__ __forceinline__ float phi_f(float x) { return x > 0.f ? x + 1.f : __expf(x); }

__device__ __forceinline__ ushort f2bf(float f) {
  unsigned u = __builtin_bit_cast(unsigned, f);
  u += 0x7FFFu + ((u >> 16) & 1u);   // round-to-nearest-even
  return (ushort)(u >> 16);
}
__device__ __forceinline__ float bf2f(ushort h) {
  unsigned u = ((unsigned)h) << 16;
  return __builtin_bit_cast(float, u);
}

// ---------------- Kernel 1: partial KV = phi(K)^T V and partial Z ------------
// Software-pipelined: loads for tile t+1 issued before LDS write/MFMA of t.
// Partials stored bf16, TRANSPOSED [e][d].
#define KT 32
#define LDK 40   // 32 + 8 pad (bf16)

__global__ __launch_bounds__(256, 3) void k1_kv(
    const float* __restrict__ Kg, const float* __restrict__ Vg,
    ushort* __restrict__ part, float* __restrict__ zpart, int nch, int ck)
{
  __shared__ ushort ktl[DIM * LDK];
  __shared__ ushort vtl[DIM * LDK];
  __shared__ float zl[DIM];

  const int wg = blockIdx.x;
  const int bh = wg / nch;
  const int c  = wg - bh * nch;
  const int t  = threadIdx.x;
  const int lane = t & 63;
  const int w  = t >> 6;          // wave 0..3 -> e range w*32..w*32+32
  const int p  = t >> 4;          // row-pair 0..15
  const int db = (t & 15) * 8;    // d base for staging

  const long base = (long)bh * NKV * DIM + (long)c * ck * DIM;
  const float* Kp = Kg + base + (long)(2 * p) * DIM + db;
  const float* Vp = Vg + base + (long)(2 * p) * DIM + db;

  if (t < DIM) zl[t] = 0.f;

  f32x4 acc[8][2];
#pragma unroll
  for (int i = 0; i < 8; i++) {
    acc[i][0] = (f32x4){0.f, 0.f, 0.f, 0.f};
    acc[i][1] = (f32x4){0.f, 0.f, 0.f, 0.f};
  }
  float zacc[8];
#pragma unroll
  for (int j = 0; j < 8; j++) zacc[j] = 0.f;

  const int kk = (lane >> 4) * 8;

  // prologue: tile 0 loads
  float4 st[8];
  st[0] = *(const float4*)(Kp);
  st[1] = *(const float4*)(Kp + 4);
  st[2] = *(const float4*)(Kp + DIM);
  st[3] = *(const float4*)(Kp + DIM + 4);
  st[4] = *(const float4*)(Vp);
  st[5] = *(const float4*)(Vp + 4);
  st[6] = *(const float4*)(Vp + DIM);
  st[7] = *(const float4*)(Vp + DIM + 4);

  __syncthreads();   // zl init visible

  for (int k0 = 0; k0 < ck; k0 += KT) {
    float k0a[8] = {st[0].x, st[0].y, st[0].z, st[0].w, st[1].x, st[1].y, st[1].z, st[1].w};
    float k1a[8] = {st[2].x, st[2].y, st[2].z, st[2].w, st[3].x, st[3].y, st[3].z, st[3].w};
    float v0a[8] = {st[4].x, st[4].y, st[4].z, st[4].w, st[5].x, st[5].y, st[5].z, st[5].w};
    float v1a[8] = {st[6].x, st[6].y, st[6].z, st[6].w, st[7].x, st[7].y, st[7].z, st[7].w};

    unsigned pkK[8], pkV[8];
#pragma unroll
    for (int j = 0; j < 8; j++) {
      ushort a = f2bf(phi_f(k0a[j]));
      ushort b = f2bf(phi_f(k1a[j]));
      zacc[j] += bf2f(a) + bf2f(b);   // Z consistent with bf16 MFMA operand
      pkK[j] = (unsigned)a | ((unsigned)b << 16);
      ushort x = f2bf(v0a[j]);
      ushort y = f2bf(v1a[j]);
      pkV[j] = (unsigned)x | ((unsigned)y << 16);
    }

    // prefetch tile t+1 (in flight across barriers + LDS ops + MFMA)
    if (k0 + KT < ck) {
      const float* kr = Kp + (long)(k0 + KT) * DIM;
      const float* vr = Vp + (long)(k0 + KT) * DIM;
      st[0] = *(const float4*)(kr);
      st[1] = *(const float4*)(kr + 4);
      st[2] = *(const float4*)(kr + DIM);
      st[3] = *(const float4*)(kr + DIM + 4);
      st[4] = *(const float4*)(vr);
      st[5] = *(const float4*)(vr + 4);
      st[6] = *(const float4*)(vr + DIM);
      st[7] = *(const float4*)(vr + DIM + 4);
    }

    __syncthreads();   // previous iteration's LDS reads done

#pragma unroll
    for (int j = 0; j < 8; j++) {
      int row = db + j;
      int col = (2 * p) ^ (((row >> 3) & 3) << 3);   // 16B-granule XOR swizzle
      *(unsigned*)&ktl[row * LDK + col] = pkK[j];
      *(unsigned*)&vtl[row * LDK + col] = pkV[j];
    }
    __syncthreads();

    bf16x8 bfr[2];
#pragma unroll
    for (int et = 0; et < 2; et++) {
      int e = w * 32 + et * 16 + (lane & 15);
      int kk2 = kk ^ (((e >> 3) & 3) << 3);
      bfr[et] = *(const bf16x8*)&vtl[e * LDK + kk2];
    }
#pragma unroll
    for (int dt = 0; dt < 8; dt++) {
      int dd = dt * 16 + (lane & 15);
      int kk2 = kk ^ (((dd >> 3) & 3) << 3);
      bf16x8 afr = *(const bf16x8*)&ktl[dd * LDK + kk2];
      acc[dt][0] = __builtin_amdgcn_mfma_f32_16x16x32_bf16(afr, bfr[0], acc[dt][0], 0, 0, 0);
      acc[dt][1] = __builtin_amdgcn_mfma_f32_16x16x32_bf16(afr, bfr[1], acc[dt][1], 0, 0, 0);
    }
  }

  // write partial KV transposed [e][d], bf16, vectorized 4-d per store
  ushort* pp = part + (long)wg * (DIM * DIM);
#pragma unroll
  for (int dt = 0; dt < 8; dt++) {
    int d0 = dt * 16 + (lane >> 4) * 4;
#pragma unroll
    for (int et = 0; et < 2; et++) {
      int e = w * 32 + et * 16 + (lane & 15);
      ushort o[4];
#pragma unroll
      for (int r = 0; r < 4; r++) o[r] = f2bf(acc[dt][et][r]);
      *(uint2*)&pp[(long)e * DIM + d0] = *(uint2*)o;
    }
  }
#pragma unroll
  for (int j = 0; j < 8; j++) atomicAdd(&zl[db + j], zacc[j]);
  __syncthreads();
  if (t < DIM) zpart[(long)wg * DIM + t] = zl[t];
}

// ------------- Reduce: sum bf16 partials (already [e][d]); emit kvt, Z ------
template<int NCH>
__global__ __launch_bounds__(256) void k_red(
    const ushort* __restrict__ part, const float* __restrict__ zpart,
    ushort* __restrict__ kvt, float* __restrict__ zout)
{
  const int bh = blockIdx.x >> 2;
  const int quad = blockIdx.x & 3;
  const int t = threadIdx.x;
  const long pbase = (long)bh * NCH * (DIM * DIM);

  // per bh: 16384 bf16 = 2048 uint4; per quad-block 512; per thread 2
#pragma unroll
  for (int i = 0; i < 2; i++) {
    int u4 = quad * 512 + t + i * 256;
    long off = pbase + (long)u4 * 8;
    float s[8] = {0.f, 0.f, 0.f, 0.f, 0.f, 0.f, 0.f, 0.f};
#pragma unroll
    for (int cc = 0; cc < NCH; cc++) {
      uint4 v = *(const uint4*)&part[off + (long)cc * (DIM * DIM)];
      unsigned ws_[4] = {v.x, v.y, v.z, v.w};
#pragma unroll
      for (int h = 0; h < 4; h++) {
        s[2 * h]     += bf2f((ushort)(ws_[h] & 0xFFFFu));
        s[2 * h + 1] += bf2f((ushort)(ws_[h] >> 16));
      }
    }
    unsigned o[4];
#pragma unroll
    for (int h = 0; h < 4; h++)
      o[h] = (unsigned)f2bf(s[2 * h]) | ((unsigned)f2bf(s[2 * h + 1]) << 16);
    *(uint4*)&kvt[(long)bh * (DIM * DIM) + (long)u4 * 8] =
        make_uint4(o[0], o[1], o[2], o[3]);
  }

  if (quad == 0 && t < DIM) {
    float s = 0.f;
#pragma unroll
    for (int cc = 0; cc < NCH; cc++)
      s += zpart[((long)bh * NCH + cc) * DIM + t];
    zout[(long)bh * DIM + t] = s;
  }
}

// --------- Kernel 2: out = (phi(Q) KV) / (phi(Q)·Z + eps) -------------------
#define QB 64
#define LDQ 136   // 128 + 8 pad

__global__ __launch_bounds__(256) void k2_fwd(
    const float* __restrict__ Qg, const ushort* __restrict__ kvt,
    const float* __restrict__ zg, float* __restrict__ outg)
{
  __shared__ ushort ql[QB * LDQ];
  __shared__ ushort kvl[DIM * LDQ];
  __shared__ float zl[DIM];
  __shared__ float dpart[4][QB];
  __shared__ float invd[QB];

  const int bid = blockIdx.x;
  const int bh = bid >> 5;
  const int q0 = (bid & 31) * QB;
  const int t = threadIdx.x;
  const int lane = t & 63;
  const int w = t >> 6;

  if (t < DIM) zl[t] = zg[(long)bh * DIM + t];

  // stage phi(Q) as bf16, row-major
  const float* Qp = Qg + ((long)bh * NQ + q0) * DIM;
#pragma unroll
  for (int i = 0; i < 8; i++) {
    int idx4 = t + i * 256;          // float4 chunk id
    int row = idx4 >> 5;
    int c4 = idx4 & 31;
    float4 v = *(const float4*)(Qp + (long)row * DIM + c4 * 4);
    ushort a = f2bf(phi_f(v.x)), b = f2bf(phi_f(v.y));
    ushort cq = f2bf(phi_f(v.z)), dq = f2bf(phi_f(v.w));
    uint2 pk;
    pk.x = (unsigned)a | ((unsigned)b << 16);
    pk.y = (unsigned)cq | ((unsigned)dq << 16);
    *(uint2*)&ql[row * LDQ + c4 * 4] = pk;
  }
  // stage KV^T (already bf16)
  const ushort* kp = kvt + (long)bh * (DIM * DIM);
#pragma unroll
  for (int i = 0; i < 8; i++) {
    int idx8 = t + i * 256;
    int row = idx8 >> 4;
    int c8 = idx8 & 15;
    uint4 vv = *(const uint4*)(kp + row * DIM + c8 * 8);
    *(uint4*)&kvl[row * LDQ + c8 * 8] = vv;
  }
  __syncthreads();

  // denominator per row
  {
    int row = t & (QB - 1);
    int q4 = t >> 6;
    float s = 0.f;
#pragma unroll
    for (int i = 0; i < 4; i++) {
      int d0 = q4 * 32 + i * 8;
      bf16x8 qv = *(const bf16x8*)&ql[row * LDQ + d0];
#pragma unroll
      for (int j = 0; j < 8; j++)
        s += bf2f((ushort)qv[j]) * zl[d0 + j];
    }
    dpart[q4][row] = s;
  }
  __syncthreads();
  if (t < QB) {
    float den = dpart[0][t] + dpart[1][t] + dpart[2][t] + dpart[3][t] + EPSV;
    invd[t] = 1.f / den;
  }
  __syncthreads();

  // numerator via MFMA: D[q][e] += A[q][d] * B[d][e]
  const int kk = (lane >> 4) * 8;
  const int qrow = w * 16 + (lane & 15);
  f32x4 acc[8];
#pragma unroll
  for (int et = 0; et < 8; et++) acc[et] = (f32x4){0.f, 0.f, 0.f, 0.f};

#pragma unroll
  for (int d0 = 0; d0 < DIM; d0 += 32) {
    bf16x8 afr = *(const bf16x8*)&ql[qrow * LDQ + d0 + kk];
#pragma unroll
    for (int et = 0; et < 8; et++) {
      int e = et * 16 + (lane & 15);
      bf16x8 bfr = *(const bf16x8*)&kvl[e * LDQ + d0 + kk];
      acc[et] = __builtin_amdgcn_mfma_f32_16x16x32_bf16(afr, bfr, acc[et], 0, 0, 0);
    }
  }

  // epilogue: scale by 1/den, store f32
  float* op = outg + ((long)bh * NQ + q0) * DIM;
#pragma unroll
  for (int et = 0; et < 8; et++) {
    int e = et * 16 + (lane & 15);
    int r0 = w * 16 + (lane >> 4) * 4;
#pragma unroll
    for (int r = 0; r < 4; r++) {
      float val = acc[et][r] * invd[r0 + r];
      op[(long)(r0 + r) * DIM + e] = val;
    }
  }
}

extern "C" void kernel_launch(void* const* d_in, const int* in_sizes, int n_in,
                              void* d_out, int out_size, void* d_ws, size_t ws_size,
                              hipStream_t stream) {
  const float* Q  = (const float*)d_in[0];
  const float* Km = (const float*)d_in[1];
  const float* Vm = (const float*)d_in[2];
  float* out = (float*)d_out;

  char* ws = (char*)d_ws;
  ushort* kvt = (ushort*)ws;                                    // 64*16384*2 = 2 MB
  float* zred = (float*)(ws + (size_t)BH * DIM * DIM * 2);      // 32 KB
  size_t fixed = (size_t)BH * DIM * DIM * 2 + (size_t)BH * DIM * 4;

  int nch = 32;
  while (nch > 1) {
    size_t need = fixed + (size_t)BH * nch * DIM * DIM * 2 + (size_t)BH * nch * DIM * 4;
    if (need <= ws_size) break;
    nch >>= 1;
  }
  ushort* partb = (ushort*)(ws + fixed);
  float* zpart = (float*)(ws + fixed + (size_t)BH * nch * DIM * DIM * 2);
  int ck = NKV / nch;

  k1_kv<<<BH * nch, 256, 0, stream>>>(Km, Vm, partb, zpart, nch, ck);

  dim3 rg(BH * 4);
  switch (nch) {
    case 32: k_red<32><<<rg, 256, 0, stream>>>(partb, zpart, kvt, zred); break;
    case 16: k_red<16><<<rg, 256, 0, stream>>>(partb, zpart, kvt, zred); break;
    case 8:  k_red<8> <<<rg, 256, 0, stream>>>(partb, zpart, kvt, zred); break;
    case 4:  k_red<4> <<<rg, 256, 0, stream>>>(partb, zpart, kvt, zred); break;
    case 2:  k_red<2> <<<rg, 256, 0, stream>>>(partb, zpart, kvt, zred); break;
    default: k_red<1> <<<rg, 256, 0, stream>>>(partb, zpart, kvt, zred); break;
  }

  k2_fwd<<<BH * 32, 256, 0, stream>>>(Q, kvt, zred, out);
}

// Round 5
// 164.151 us; speedup vs baseline: 1.1941x; 1.1941x over previous
//
#include <hip/hip_runtime.h>
#include <hip/hip_bf16.h>

#define BH 64
#define NKV 8192
#define NQ 2048
#define DIM 128
#define EPSV 1e-6f

typedef __attribute__((ext_vector_type(8))) short bf16x8;
typedef __attribute__((ext_vector_type(4))) float f32x4;

__device__ __forceinline__ float phi_f(float x) { return x > 0.f ? x + 1.f : __expf(x); }

__device__ __forceinline__ ushort f2bf(float f) {
  unsigned u = __builtin_bit_cast(unsigned, f);
  u += 0x7FFFu + ((u >> 16) & 1u);   // round-to-nearest-even
  return (ushort)(u >> 16);
}
__device__ __forceinline__ float bf2f(ushort h) {
  unsigned u = ((unsigned)h) << 16;
  return __builtin_bit_cast(float, u);
}

// ---------------- Kernel 1: partial KV = phi(K)^T V and partial Z ------------
// 512 threads: waves 0-3 stage K, waves 4-7 stage V. Depth-2 register
// prefetch (stA/stB), double-buffered bf16 LDS tiles, ONE barrier per k-tile.
// Partials stored bf16, TRANSPOSED [e][d].
#define KT 32
#define LDK 40   // 32 + 8 pad (bf16)

__global__ __launch_bounds__(512, 4) void k1_kv(
    const float* __restrict__ Kg, const float* __restrict__ Vg,
    ushort* __restrict__ part, float* __restrict__ zpart, int nch, int ck)
{
  __shared__ ushort ktl[2][DIM * LDK];
  __shared__ ushort vtl[2][DIM * LDK];
  __shared__ float zl[DIM];

  const int wg = blockIdx.x;
  const int bh = wg / nch;
  const int c  = wg - bh * nch;
  const int t  = threadIdx.x;
  const int lane = t & 63;
  const int w  = t >> 6;            // wave 0..7 -> e-tile = w*16
  const int isV = t >> 8;           // 0: stage K, 1: stage V (wave-uniform)
  const int ts = t & 255;
  const int p  = ts >> 4;           // row-pair 0..15
  const int db = (ts & 15) * 8;     // d base for staging

  const long base = (long)bh * NKV * DIM + (long)c * ck * DIM;
  const float* Sp = (isV ? Vg : Kg) + base + (long)(2 * p) * DIM + db;

  if (t < DIM) zl[t] = 0.f;

  f32x4 acc[8];
#pragma unroll
  for (int i = 0; i < 8; i++) acc[i] = (f32x4){0.f, 0.f, 0.f, 0.f};
  float zacc[8];
#pragma unroll
  for (int j = 0; j < 8; j++) zacc[j] = 0.f;

  const int kk = (lane >> 4) * 8;
  const int e  = w * 16 + (lane & 15);
  const int kke = kk ^ (((e >> 3) & 3) << 3);

  const int ntile = ck / KT;        // even for all nch in {1,2,4,8,16,32}

  // rolling depth-2 staging buffers (2 rows x 8 d of one matrix)
  float4 stA[4], stB[4];
#define LOADT(dst, ti) do {                                  \
    const float* _s = Sp + (long)(ti) * (KT * DIM);          \
    dst[0] = *(const float4*)(_s);                           \
    dst[1] = *(const float4*)(_s + 4);                       \
    dst[2] = *(const float4*)(_s + DIM);                     \
    dst[3] = *(const float4*)(_s + DIM + 4);                 \
  } while (0)

  LOADT(stA, 0);
  LOADT(stB, 1);

#define PROC(stX, ti, bufi) do {                                           \
    float r0[8] = {stX[0].x, stX[0].y, stX[0].z, stX[0].w,                 \
                   stX[1].x, stX[1].y, stX[1].z, stX[1].w};                \
    float r1[8] = {stX[2].x, stX[2].y, stX[2].z, stX[2].w,                 \
                   stX[3].x, stX[3].y, stX[3].z, stX[3].w};                \
    unsigned pk[8];                                                        \
    if (isV == 0) {                                                        \
      _Pragma("unroll")                                                    \
      for (int j = 0; j < 8; j++) {                                        \
        ushort a = f2bf(phi_f(r0[j]));                                     \
        ushort b = f2bf(phi_f(r1[j]));                                     \
        zacc[j] += bf2f(a) + bf2f(b);                                      \
        pk[j] = (unsigned)a | ((unsigned)b << 16);                         \
      }                                                                    \
    } else {                                                               \
      _Pragma("unroll")                                                    \
      for (int j = 0; j < 8; j++) {                                        \
        ushort a = f2bf(r0[j]);                                            \
        ushort b = f2bf(r1[j]);                                            \
        pk[j] = (unsigned)a | ((unsigned)b << 16);                         \
      }                                                                    \
    }                                                                      \
    if ((ti) + 2 < ntile) LOADT(stX, (ti) + 2);                            \
    ushort* dst = isV ? vtl[bufi] : ktl[bufi];                             \
    _Pragma("unroll")                                                      \
    for (int j = 0; j < 8; j++) {                                          \
      int row = db + j;                                                    \
      int col = (2 * p) ^ (((row >> 3) & 3) << 3);                         \
      *(unsigned*)&dst[row * LDK + col] = pk[j];                           \
    }                                                                      \
    __syncthreads();                                                       \
    bf16x8 bfr = *(const bf16x8*)&vtl[bufi][e * LDK + kke];                \
    _Pragma("unroll")                                                      \
    for (int dt = 0; dt < 8; dt++) {                                       \
      int dd = dt * 16 + (lane & 15);                                      \
      int kkd = kk ^ (((dd >> 3) & 3) << 3);                               \
      bf16x8 afr = *(const bf16x8*)&ktl[bufi][dd * LDK + kkd];             \
      acc[dt] = __builtin_amdgcn_mfma_f32_16x16x32_bf16(afr, bfr, acc[dt], 0, 0, 0); \
    }                                                                      \
  } while (0)

  for (int ti = 0; ti < ntile; ti += 2) {
    PROC(stA, ti, 0);
    PROC(stB, ti + 1, 1);
  }

  // write partial KV transposed [e][d], bf16, vectorized 4-d per store
  ushort* pp = part + (long)wg * (DIM * DIM);
#pragma unroll
  for (int dt = 0; dt < 8; dt++) {
    int d0 = dt * 16 + (lane >> 4) * 4;
    ushort o[4];
#pragma unroll
    for (int r = 0; r < 4; r++) o[r] = f2bf(acc[dt][r]);
    *(uint2*)&pp[(long)e * DIM + d0] = *(uint2*)o;
  }
  if (isV == 0) {
#pragma unroll
    for (int j = 0; j < 8; j++) atomicAdd(&zl[db + j], zacc[j]);
  }
  __syncthreads();
  if (t < DIM) zpart[(long)wg * DIM + t] = zl[t];
}

// ------------- Reduce: sum bf16 partials (already [e][d]); emit kvt, Z ------
template<int NCH>
__global__ __launch_bounds__(256) void k_red(
    const ushort* __restrict__ part, const float* __restrict__ zpart,
    ushort* __restrict__ kvt, float* __restrict__ zout)
{
  const int bh = blockIdx.x >> 2;
  const int quad = blockIdx.x & 3;
  const int t = threadIdx.x;
  const long pbase = (long)bh * NCH * (DIM * DIM);

  // per bh: 16384 bf16 = 2048 uint4; per quad-block 512; per thread 2
#pragma unroll
  for (int i = 0; i < 2; i++) {
    int u4 = quad * 512 + t + i * 256;
    long off = pbase + (long)u4 * 8;
    float s[8] = {0.f, 0.f, 0.f, 0.f, 0.f, 0.f, 0.f, 0.f};
#pragma unroll
    for (int cc = 0; cc < NCH; cc++) {
      uint4 v = *(const uint4*)&part[off + (long)cc * (DIM * DIM)];
      unsigned ws_[4] = {v.x, v.y, v.z, v.w};
#pragma unroll
      for (int h = 0; h < 4; h++) {
        s[2 * h]     += bf2f((ushort)(ws_[h] & 0xFFFFu));
        s[2 * h + 1] += bf2f((ushort)(ws_[h] >> 16));
      }
    }
    unsigned o[4];
#pragma unroll
    for (int h = 0; h < 4; h++)
      o[h] = (unsigned)f2bf(s[2 * h]) | ((unsigned)f2bf(s[2 * h + 1]) << 16);
    *(uint4*)&kvt[(long)bh * (DIM * DIM) + (long)u4 * 8] =
        make_uint4(o[0], o[1], o[2], o[3]);
  }

  if (quad == 0 && t < DIM) {
    float s = 0.f;
#pragma unroll
    for (int cc = 0; cc < NCH; cc++)
      s += zpart[((long)bh * NCH + cc) * DIM + t];
    zout[(long)bh * DIM + t] = s;
  }
}

// --------- Kernel 2: out = (phi(Q) KV) / (phi(Q)·Z + eps) -------------------
#define QB 64
#define LDQ 136   // 128 + 8 pad

__global__ __launch_bounds__(256) void k2_fwd(
    const float* __restrict__ Qg, const ushort* __restrict__ kvt,
    const float* __restrict__ zg, float* __restrict__ outg)
{
  __shared__ ushort ql[QB * LDQ];
  __shared__ ushort kvl[DIM * LDQ];
  __shared__ float zl[DIM];
  __shared__ float dpart[4][QB];
  __shared__ float invd[QB];

  const int bid = blockIdx.x;
  const int bh = bid >> 5;
  const int q0 = (bid & 31) * QB;
  const int t = threadIdx.x;
  const int lane = t & 63;
  const int w = t >> 6;

  if (t < DIM) zl[t] = zg[(long)bh * DIM + t];

  // stage phi(Q) as bf16, row-major
  const float* Qp = Qg + ((long)bh * NQ + q0) * DIM;
#pragma unroll
  for (int i = 0; i < 8; i++) {
    int idx4 = t + i * 256;          // float4 chunk id
    int row = idx4 >> 5;
    int c4 = idx4 & 31;
    float4 v = *(const float4*)(Qp + (long)row * DIM + c4 * 4);
    ushort a = f2bf(phi_f(v.x)), b = f2bf(phi_f(v.y));
    ushort cq = f2bf(phi_f(v.z)), dq = f2bf(phi_f(v.w));
    uint2 pk;
    pk.x = (unsigned)a | ((unsigned)b << 16);
    pk.y = (unsigned)cq | ((unsigned)dq << 16);
    *(uint2*)&ql[row * LDQ + c4 * 4] = pk;
  }
  // stage KV^T (already bf16)
  const ushort* kp = kvt + (long)bh * (DIM * DIM);
#pragma unroll
  for (int i = 0; i < 8; i++) {
    int idx8 = t + i * 256;
    int row = idx8 >> 4;
    int c8 = idx8 & 15;
    uint4 vv = *(const uint4*)(kp + row * DIM + c8 * 8);
    *(uint4*)&kvl[row * LDQ + c8 * 8] = vv;
  }
  __syncthreads();

  // denominator per row
  {
    int row = t & (QB - 1);
    int q4 = t >> 6;
    float s = 0.f;
#pragma unroll
    for (int i = 0; i < 4; i++) {
      int d0 = q4 * 32 + i * 8;
      bf16x8 qv = *(const bf16x8*)&ql[row * LDQ + d0];
#pragma unroll
      for (int j = 0; j < 8; j++)
        s += bf2f((ushort)qv[j]) * zl[d0 + j];
    }
    dpart[q4][row] = s;
  }
  __syncthreads();
  if (t < QB) {
    float den = dpart[0][t] + dpart[1][t] + dpart[2][t] + dpart[3][t] + EPSV;
    invd[t] = 1.f / den;
  }
  __syncthreads();

  // numerator via MFMA: D[q][e] += A[q][d] * B[d][e]
  const int kk = (lane >> 4) * 8;
  const int qrow = w * 16 + (lane & 15);
  f32x4 acc[8];
#pragma unroll
  for (int et = 0; et < 8; et++) acc[et] = (f32x4){0.f, 0.f, 0.f, 0.f};

#pragma unroll
  for (int d0 = 0; d0 < DIM; d0 += 32) {
    bf16x8 afr = *(const bf16x8*)&ql[qrow * LDQ + d0 + kk];
#pragma unroll
    for (int et = 0; et < 8; et++) {
      int e = et * 16 + (lane & 15);
      bf16x8 bfr = *(const bf16x8*)&kvl[e * LDQ + d0 + kk];
      acc[et] = __builtin_amdgcn_mfma_f32_16x16x32_bf16(afr, bfr, acc[et], 0, 0, 0);
    }
  }

  // epilogue: scale by 1/den, store f32
  float* op = outg + ((long)bh * NQ + q0) * DIM;
#pragma unroll
  for (int et = 0; et < 8; et++) {
    int e = et * 16 + (lane & 15);
    int r0 = w * 16 + (lane >> 4) * 4;
#pragma unroll
    for (int r = 0; r < 4; r++) {
      float val = acc[et][r] * invd[r0 + r];
      op[(long)(r0 + r) * DIM + e] = val;
    }
  }
}

extern "C" void kernel_launch(void* const* d_in, const int* in_sizes, int n_in,
                              void* d_out, int out_size, void* d_ws, size_t ws_size,
                              hipStream_t stream) {
  const float* Q  = (const float*)d_in[0];
  const float* Km = (const float*)d_in[1];
  const float* Vm = (const float*)d_in[2];
  float* out = (float*)d_out;

  char* ws = (char*)d_ws;
  ushort* kvt = (ushort*)ws;                                    // 64*16384*2 = 2 MB
  float* zred = (float*)(ws + (size_t)BH * DIM * DIM * 2);      // 32 KB
  size_t fixed = (size_t)BH * DIM * DIM * 2 + (size_t)BH * DIM * 4;

  int nch = 16;
  while (nch > 1) {
    size_t need = fixed + (size_t)BH * nch * DIM * DIM * 2 + (size_t)BH * nch * DIM * 4;
    if (need <= ws_size) break;
    nch >>= 1;
  }
  ushort* partb = (ushort*)(ws + fixed);
  float* zpart = (float*)(ws + fixed + (size_t)BH * nch * DIM * DIM * 2);
  int ck = NKV / nch;

  k1_kv<<<BH * nch, 512, 0, stream>>>(Km, Vm, partb, zpart, nch, ck);

  dim3 rg(BH * 4);
  switch (nch) {
    case 16: k_red<16><<<rg, 256, 0, stream>>>(partb, zpart, kvt, zred); break;
    case 8:  k_red<8> <<<rg, 256, 0, stream>>>(partb, zpart, kvt, zred); break;
    case 4:  k_red<4> <<<rg, 256, 0, stream>>>(partb, zpart, kvt, zred); break;
    case 2:  k_red<2> <<<rg, 256, 0, stream>>>(partb, zpart, kvt, zred); break;
    default: k_red<1> <<<rg, 256, 0, stream>>>(partb, zpart, kvt, zred); break;
  }

  k2_fwd<<<BH * 32, 256, 0, stream>>>(Q, kvt, zred, out);
}

// Round 7
// 155.136 us; speedup vs baseline: 1.2635x; 1.0581x over previous
//
#include <hip/hip_runtime.h>
#include <hip/hip_bf16.h>

#define BH 64
#define NKV 8192
#define NQ 2048
#define DIM 128
#define EPSV 1e-6f

typedef __attribute__((ext_vector_type(8))) short bf16x8;
typedef __attribute__((ext_vector_type(4))) float f32x4;

__device__ __forceinline__ float phi_f(float x) { return x > 0.f ? x + 1.f : __expf(x); }

__device__ __forceinline__ ushort f2bf(float f) {
  unsigned u = __builtin_bit_cast(unsigned, f);
  u += 0x7FFFu + ((u >> 16) & 1u);   // round-to-nearest-even
  return (ushort)(u >> 16);
}
__device__ __forceinline__ float bf2f(ushort h) {
  unsigned u = ((unsigned)h) << 16;
  return __builtin_bit_cast(float, u);
}

// ---------------- Kernel 1: partial KV = phi(K)^T V and partial Z ------------
// 512 threads: waves 0-3 stage K, waves 4-7 stage V. Depth-2 register
// prefetch, double-buffered bf16 LDS, ONE barrier per k-tile.
// K/V loads NONTEMPORAL (read-once streaming; test L3-bypass theory).
// LDS = 40960 B exactly -> 4 blocks/CU, no residency tail.
#define KT 32
#define LDK 40   // 32 + 8 pad (bf16)

__global__ __launch_bounds__(512, 4) void k1_kv(
    const float* __restrict__ Kg, const float* __restrict__ Vg,
    ushort* __restrict__ part, float* __restrict__ zpart, int nch, int ck)
{
  __shared__ ushort ktl[2][DIM * LDK];
  __shared__ ushort vtl[2][DIM * LDK];

  const int wg = blockIdx.x;
  const int bh = wg / nch;
  const int c  = wg - bh * nch;
  const int t  = threadIdx.x;
  const int lane = t & 63;
  const int w  = t >> 6;            // wave 0..7 -> e-tile = w*16
  const int isV = t >> 8;           // 0: stage K, 1: stage V (wave-uniform)
  const int ts = t & 255;
  const int p  = ts >> 4;           // row-pair 0..15
  const int db = (ts & 15) * 8;     // d base for staging

  const long base = (long)bh * NKV * DIM + (long)c * ck * DIM;
  const float* Sp = (isV ? Vg : Kg) + base + (long)(2 * p) * DIM + db;

  f32x4 acc[8];
#pragma unroll
  for (int i = 0; i < 8; i++) acc[i] = (f32x4){0.f, 0.f, 0.f, 0.f};
  float zacc[8];
#pragma unroll
  for (int j = 0; j < 8; j++) zacc[j] = 0.f;

  const int kk = (lane >> 4) * 8;
  const int e  = w * 16 + (lane & 15);
  const int kke = kk ^ (((e >> 3) & 3) << 3);

  const int ntile = ck / KT;        // even for all nch in {1,2,4,8,16,32}

  // rolling depth-2 staging buffers (2 rows x 8 d of one matrix)
  f32x4 stA[4], stB[4];
#define LOADT(dst, ti) do {                                            \
    const float* _s = Sp + (long)(ti) * (KT * DIM);                    \
    dst[0] = __builtin_nontemporal_load((const f32x4*)(_s));           \
    dst[1] = __builtin_nontemporal_load((const f32x4*)(_s + 4));       \
    dst[2] = __builtin_nontemporal_load((const f32x4*)(_s + DIM));     \
    dst[3] = __builtin_nontemporal_load((const f32x4*)(_s + DIM + 4)); \
  } while (0)

  LOADT(stA, 0);
  LOADT(stB, 1);

#define PROC(stX, ti, bufi) do {                                           \
    float r0[8] = {stX[0].x, stX[0].y, stX[0].z, stX[0].w,                 \
                   stX[1].x, stX[1].y, stX[1].z, stX[1].w};                \
    float r1[8] = {stX[2].x, stX[2].y, stX[2].z, stX[2].w,                 \
                   stX[3].x, stX[3].y, stX[3].z, stX[3].w};                \
    unsigned pk[8];                                                        \
    if (isV == 0) {                                                        \
      _Pragma("unroll")                                                    \
      for (int j = 0; j < 8; j++) {                                        \
        ushort a = f2bf(phi_f(r0[j]));                                     \
        ushort b = f2bf(phi_f(r1[j]));                                     \
        zacc[j] += bf2f(a) + bf2f(b);                                      \
        pk[j] = (unsigned)a | ((unsigned)b << 16);                         \
      }                                                                    \
    } else {                                                               \
      _Pragma("unroll")                                                    \
      for (int j = 0; j < 8; j++) {                                        \
        ushort a = f2bf(r0[j]);                                            \
        ushort b = f2bf(r1[j]);                                            \
        pk[j] = (unsigned)a | ((unsigned)b << 16);                         \
      }                                                                    \
    }                                                                      \
    if ((ti) + 2 < ntile) LOADT(stX, (ti) + 2);                            \
    ushort* dst = isV ? vtl[bufi] : ktl[bufi];                             \
    _Pragma("unroll")                                                      \
    for (int j = 0; j < 8; j++) {                                          \
      int row = db + j;                                                    \
      int col = (2 * p) ^ (((row >> 3) & 3) << 3);                         \
      *(unsigned*)&dst[row * LDK + col] = pk[j];                           \
    }                                                                      \
    __syncthreads();                                                       \
    bf16x8 bfr = *(const bf16x8*)&vtl[bufi][e * LDK + kke];                \
    _Pragma("unroll")                                                      \
    for (int dt = 0; dt < 8; dt++) {                                       \
      int dd = dt * 16 + (lane & 15);                                      \
      int kkd = kk ^ (((dd >> 3) & 3) << 3);                               \
      bf16x8 afr = *(const bf16x8*)&ktl[bufi][dd * LDK + kkd];             \
      acc[dt] = __builtin_amdgcn_mfma_f32_16x16x32_bf16(afr, bfr, acc[dt], 0, 0, 0); \
    }                                                                      \
  } while (0)

  for (int ti = 0; ti < ntile; ti += 2) {
    PROC(stA, ti, 0);
    PROC(stB, ti + 1, 1);
  }

  // write partial KV transposed [e][d], bf16, vectorized 4-d per store
  ushort* pp = part + (long)wg * (DIM * DIM);
#pragma unroll
  for (int dt = 0; dt < 8; dt++) {
    int d0 = dt * 16 + (lane >> 4) * 4;
    ushort o[4];
#pragma unroll
    for (int r = 0; r < 4; r++) o[r] = f2bf(acc[dt][r]);
    *(uint2*)&pp[(long)e * DIM + d0] = *(uint2*)o;
  }

  // Z: intra-wave reduce over the 4 row-pair groups, per-wave slice to zpart
  if (isV == 0) {
    float zr[8];
#pragma unroll
    for (int j = 0; j < 8; j++) {
      float z = zacc[j];
      z += __shfl_xor(z, 16, 64);
      z += __shfl_xor(z, 32, 64);
      zr[j] = z;
    }
    if ((lane & 48) == 0) {   // lanes 0..15
      float* zp = zpart + ((long)wg * 4 + w) * DIM + (lane & 15) * 8;
#pragma unroll
      for (int j = 0; j < 8; j++) zp[j] = zr[j];
    }
  }
}

// ------------- Reduce: sum bf16 partials (already [e][d]); emit kvt, Z ------
template<int NCH>
__global__ __launch_bounds__(256) void k_red(
    const ushort* __restrict__ part, const float* __restrict__ zpart,
    ushort* __restrict__ kvt, float* __restrict__ zout)
{
  const int bh = blockIdx.x >> 2;
  const int quad = blockIdx.x & 3;
  const int t = threadIdx.x;
  const long pbase = (long)bh * NCH * (DIM * DIM);

  // per bh: 16384 bf16 = 2048 uint4; per quad-block 512; per thread 2
#pragma unroll
  for (int i = 0; i < 2; i++) {
    int u4 = quad * 512 + t + i * 256;
    long off = pbase + (long)u4 * 8;
    float s[8] = {0.f, 0.f, 0.f, 0.f, 0.f, 0.f, 0.f, 0.f};
#pragma unroll
    for (int cc = 0; cc < NCH; cc++) {
      uint4 v = *(const uint4*)&part[off + (long)cc * (DIM * DIM)];
      unsigned ws_[4] = {v.x, v.y, v.z, v.w};
#pragma unroll
      for (int h = 0; h < 4; h++) {
        s[2 * h]     += bf2f((ushort)(ws_[h] & 0xFFFFu));
        s[2 * h + 1] += bf2f((ushort)(ws_[h] >> 16));
      }
    }
    unsigned o[4];
#pragma unroll
    for (int h = 0; h < 4; h++)
      o[h] = (unsigned)f2bf(s[2 * h]) | ((unsigned)f2bf(s[2 * h + 1]) << 16);
    *(uint4*)&kvt[(long)bh * (DIM * DIM) + (long)u4 * 8] =
        make_uint4(o[0], o[1], o[2], o[3]);
  }

  if (quad == 0 && t < DIM) {
    float s = 0.f;
#pragma unroll
    for (int cc = 0; cc < NCH; cc++) {
#pragma unroll
      for (int wv = 0; wv < 4; wv++)
        s += zpart[(((long)bh * NCH + cc) * 4 + wv) * DIM + t];
    }
    zout[(long)bh * DIM + t] = s;
  }
}

// --------- Kernel 2: out = (phi(Q) KV) / (phi(Q)·Z + eps) -------------------
#define QB 64
#define LDQ 136   // 128 + 8 pad

__global__ __launch_bounds__(256) void k2_fwd(
    const float* __restrict__ Qg, const ushort* __restrict__ kvt,
    const float* __restrict__ zg, float* __restrict__ outg)
{
  __shared__ ushort ql[QB * LDQ];
  __shared__ ushort kvl[DIM * LDQ];
  __shared__ float zl[DIM];
  __shared__ float dpart[4][QB];
  __shared__ float invd[QB];

  const int bid = blockIdx.x;
  const int bh = bid >> 5;
  const int q0 = (bid & 31) * QB;
  const int t = threadIdx.x;
  const int lane = t & 63;
  const int w = t >> 6;

  if (t < DIM) zl[t] = zg[(long)bh * DIM + t];

  // stage phi(Q) as bf16, row-major
  const float* Qp = Qg + ((long)bh * NQ + q0) * DIM;
#pragma unroll
  for (int i = 0; i < 8; i++) {
    int idx4 = t + i * 256;          // float4 chunk id
    int row = idx4 >> 5;
    int c4 = idx4 & 31;
    float4 v = *(const float4*)(Qp + (long)row * DIM + c4 * 4);
    ushort a = f2bf(phi_f(v.x)), b = f2bf(phi_f(v.y));
    ushort cq = f2bf(phi_f(v.z)), dq = f2bf(phi_f(v.w));
    uint2 pk;
    pk.x = (unsigned)a | ((unsigned)b << 16);
    pk.y = (unsigned)cq | ((unsigned)dq << 16);
    *(uint2*)&ql[row * LDQ + c4 * 4] = pk;
  }
  // stage KV^T (already bf16)
  const ushort* kp = kvt + (long)bh * (DIM * DIM);
#pragma unroll
  for (int i = 0; i < 8; i++) {
    int idx8 = t + i * 256;
    int row = idx8 >> 4;
    int c8 = idx8 & 15;
    uint4 vv = *(const uint4*)(kp + row * DIM + c8 * 8);
    *(uint4*)&kvl[row * LDQ + c8 * 8] = vv;
  }
  __syncthreads();

  // denominator per row
  {
    int row = t & (QB - 1);
    int q4 = t >> 6;
    float s = 0.f;
#pragma unroll
    for (int i = 0; i < 4; i++) {
      int d0 = q4 * 32 + i * 8;
      bf16x8 qv = *(const bf16x8*)&ql[row * LDQ + d0];
#pragma unroll
      for (int j = 0; j < 8; j++)
        s += bf2f((ushort)qv[j]) * zl[d0 + j];
    }
    dpart[q4][row] = s;
  }
  __syncthreads();
  if (t < QB) {
    float den = dpart[0][t] + dpart[1][t] + dpart[2][t] + dpart[3][t] + EPSV;
    invd[t] = 1.f / den;
  }
  __syncthreads();

  // numerator via MFMA: D[q][e] += A[q][d] * B[d][e]
  const int kk = (lane >> 4) * 8;
  const int qrow = w * 16 + (lane & 15);
  f32x4 acc[8];
#pragma unroll
  for (int et = 0; et < 8; et++) acc[et] = (f32x4){0.f, 0.f, 0.f, 0.f};

#pragma unroll
  for (int d0 = 0; d0 < DIM; d0 += 32) {
    bf16x8 afr = *(const bf16x8*)&ql[qrow * LDQ + d0 + kk];
#pragma unroll
    for (int et = 0; et < 8; et++) {
      int e = et * 16 + (lane & 15);
      bf16x8 bfr = *(const bf16x8*)&kvl[e * LDQ + d0 + kk];
      acc[et] = __builtin_amdgcn_mfma_f32_16x16x32_bf16(afr, bfr, acc[et], 0, 0, 0);
    }
  }

  // epilogue: scale by 1/den, store f32
  float* op = outg + ((long)bh * NQ + q0) * DIM;
#pragma unroll
  for (int et = 0; et < 8; et++) {
    int e = et * 16 + (lane & 15);
    int r0 = w * 16 + (lane >> 4) * 4;
#pragma unroll
    for (int r = 0; r < 4; r++) {
      float val = acc[et][r] * invd[r0 + r];
      op[(long)(r0 + r) * DIM + e] = val;
    }
  }
}

extern "C" void kernel_launch(void* const* d_in, const int* in_sizes, int n_in,
                              void* d_out, int out_size, void* d_ws, size_t ws_size,
                              hipStream_t stream) {
  const float* Q  = (const float*)d_in[0];
  const float* Km = (const float*)d_in[1];
  const float* Vm = (const float*)d_in[2];
  float* out = (float*)d_out;

  char* ws = (char*)d_ws;
  ushort* kvt = (ushort*)ws;                                    // 64*16384*2 = 2 MB
  float* zred = (float*)(ws + (size_t)BH * DIM * DIM * 2);      // 32 KB
  size_t fixed = (size_t)BH * DIM * DIM * 2 + (size_t)BH * DIM * 4;

  int nch = 16;
  while (nch > 1) {
    size_t need = fixed + (size_t)BH * nch * DIM * DIM * 2
                + (size_t)BH * nch * 4 * DIM * 4;
    if (need <= ws_size) break;
    nch >>= 1;
  }
  ushort* partb = (ushort*)(ws + fixed);
  float* zpart = (float*)(ws + fixed + (size_t)BH * nch * DIM * DIM * 2);
  int ck = NKV / nch;

  k1_kv<<<BH * nch, 512, 0, stream>>>(Km, Vm, partb, zpart, nch, ck);

  dim3 rg(BH * 4);
  switch (nch) {
    case 16: k_red<16><<<rg, 256, 0, stream>>>(partb, zpart, kvt, zred); break;
    case 8:  k_red<8> <<<rg, 256, 0, stream>>>(partb, zpart, kvt, zred); break;
    case 4:  k_red<4> <<<rg, 256, 0, stream>>>(partb, zpart, kvt, zred); break;
    case 2:  k_red<2> <<<rg, 256, 0, stream>>>(partb, zpart, kvt, zred); break;
    default: k_red<1> <<<rg, 256, 0, stream>>>(partb, zpart, kvt, zred); break;
  }

  k2_fwd<<<BH * 32, 256, 0, stream>>>(Q, kvt, zred, out);
}

// Round 8
// 155.019 us; speedup vs baseline: 1.2644x; 1.0008x over previous
//
#include <hip/hip_runtime.h>
#include <hip/hip_bf16.h>

#define BH 64
#define NKV 8192
#define NQ 2048
#define DIM 128
#define EPSV 1e-6f

typedef __attribute__((ext_vector_type(8))) short bf16x8;
typedef __attribute__((ext_vector_type(4))) float f32x4;

__device__ __forceinline__ float phi_f(float x) { return x > 0.f ? x + 1.f : __expf(x); }

__device__ __forceinline__ ushort f2bf(float f) {
  unsigned u = __builtin_bit_cast(unsigned, f);
  u += 0x7FFFu + ((u >> 16) & 1u);   // round-to-nearest-even
  return (ushort)(u >> 16);
}
__device__ __forceinline__ float bf2f(ushort h) {
  unsigned u = ((unsigned)h) << 16;
  return __builtin_bit_cast(float, u);
}

// ---------------- Kernel 1: partial KV = phi(K)^T V and partial Z ------------
// 512 threads: waves 0-3 stage K, waves 4-7 stage V. Depth-2 register
// prefetch, double-buffered bf16 LDS, ONE barrier per k-tile, nt loads.
// LDK=32 (no pad): XOR swizzle keeps b128 reads conflict-free; LDS=32768B
// (+~512B runtime) -> 4 blocks/CU, grid 1024 = exactly one resident round.
#define KT 32
#define LDK 32

__global__ __launch_bounds__(512, 4) void k1_kv(
    const float* __restrict__ Kg, const float* __restrict__ Vg,
    ushort* __restrict__ part, float* __restrict__ zpart, int nch, int ck)
{
  __shared__ ushort ktl[2][DIM * LDK];
  __shared__ ushort vtl[2][DIM * LDK];

  const int wg = blockIdx.x;
  const int bh = wg / nch;
  const int c  = wg - bh * nch;
  const int t  = threadIdx.x;
  const int lane = t & 63;
  const int w  = t >> 6;            // wave 0..7 -> e-tile = w*16
  const int isV = t >> 8;           // 0: stage K, 1: stage V (wave-uniform)
  const int ts = t & 255;
  const int p  = ts >> 4;           // row-pair 0..15
  const int db = (ts & 15) * 8;     // d base for staging

  const long base = (long)bh * NKV * DIM + (long)c * ck * DIM;
  const float* Sp = (isV ? Vg : Kg) + base + (long)(2 * p) * DIM + db;

  f32x4 acc[8];
#pragma unroll
  for (int i = 0; i < 8; i++) acc[i] = (f32x4){0.f, 0.f, 0.f, 0.f};
  float zacc[8];
#pragma unroll
  for (int j = 0; j < 8; j++) zacc[j] = 0.f;

  const int kk = (lane >> 4) * 8;
  const int e  = w * 16 + (lane & 15);
  const int kke = kk ^ (((e >> 3) & 3) << 3);

  const int ntile = ck / KT;        // even for all nch in {1,2,4,8,16,32}

  // rolling depth-2 staging buffers (2 rows x 8 d of one matrix)
  f32x4 stA[4], stB[4];
#define LOADT(dst, ti) do {                                            \
    const float* _s = Sp + (long)(ti) * (KT * DIM);                    \
    dst[0] = __builtin_nontemporal_load((const f32x4*)(_s));           \
    dst[1] = __builtin_nontemporal_load((const f32x4*)(_s + 4));       \
    dst[2] = __builtin_nontemporal_load((const f32x4*)(_s + DIM));     \
    dst[3] = __builtin_nontemporal_load((const f32x4*)(_s + DIM + 4)); \
  } while (0)

  LOADT(stA, 0);
  LOADT(stB, 1);

#define PROC(stX, ti, bufi) do {                                           \
    float r0[8] = {stX[0].x, stX[0].y, stX[0].z, stX[0].w,                 \
                   stX[1].x, stX[1].y, stX[1].z, stX[1].w};                \
    float r1[8] = {stX[2].x, stX[2].y, stX[2].z, stX[2].w,                 \
                   stX[3].x, stX[3].y, stX[3].z, stX[3].w};                \
    unsigned pk[8];                                                        \
    if (isV == 0) {                                                        \
      _Pragma("unroll")                                                    \
      for (int j = 0; j < 8; j++) {                                        \
        ushort a = f2bf(phi_f(r0[j]));                                     \
        ushort b = f2bf(phi_f(r1[j]));                                     \
        zacc[j] += bf2f(a) + bf2f(b);                                      \
        pk[j] = (unsigned)a | ((unsigned)b << 16);                         \
      }                                                                    \
    } else {                                                               \
      _Pragma("unroll")                                                    \
      for (int j = 0; j < 8; j++) {                                        \
        ushort a = f2bf(r0[j]);                                            \
        ushort b = f2bf(r1[j]);                                            \
        pk[j] = (unsigned)a | ((unsigned)b << 16);                         \
      }                                                                    \
    }                                                                      \
    if ((ti) + 2 < ntile) LOADT(stX, (ti) + 2);                            \
    ushort* dst = isV ? vtl[bufi] : ktl[bufi];                             \
    _Pragma("unroll")                                                      \
    for (int j = 0; j < 8; j++) {                                          \
      int row = db + j;                                                    \
      int col = (2 * p) ^ (((row >> 3) & 3) << 3);                         \
      *(unsigned*)&dst[row * LDK + col] = pk[j];                           \
    }                                                                      \
    __syncthreads();                                                       \
    bf16x8 bfr = *(const bf16x8*)&vtl[bufi][e * LDK + kke];                \
    _Pragma("unroll")                                                      \
    for (int dt = 0; dt < 8; dt++) {                                       \
      int dd = dt * 16 + (lane & 15);                                      \
      int kkd = kk ^ (((dd >> 3) & 3) << 3);                               \
      bf16x8 afr = *(const bf16x8*)&ktl[bufi][dd * LDK + kkd];             \
      acc[dt] = __builtin_amdgcn_mfma_f32_16x16x32_bf16(afr, bfr, acc[dt], 0, 0, 0); \
    }                                                                      \
  } while (0)

  for (int ti = 0; ti < ntile; ti += 2) {
    PROC(stA, ti, 0);
    PROC(stB, ti + 1, 1);
  }

  // write partial KV transposed [e][d], bf16, vectorized 4-d per store
  ushort* pp = part + (long)wg * (DIM * DIM);
#pragma unroll
  for (int dt = 0; dt < 8; dt++) {
    int d0 = dt * 16 + (lane >> 4) * 4;
    ushort o[4];
#pragma unroll
    for (int r = 0; r < 4; r++) o[r] = f2bf(acc[dt][r]);
    *(uint2*)&pp[(long)e * DIM + d0] = *(uint2*)o;
  }

  // Z: intra-wave reduce over the 4 row-pair groups, per-wave slice to zpart
  if (isV == 0) {
    float zr[8];
#pragma unroll
    for (int j = 0; j < 8; j++) {
      float z = zacc[j];
      z += __shfl_xor(z, 16, 64);
      z += __shfl_xor(z, 32, 64);
      zr[j] = z;
    }
    if ((lane & 48) == 0) {   // lanes 0..15
      float* zp = zpart + ((long)wg * 4 + w) * DIM + (lane & 15) * 8;
#pragma unroll
      for (int j = 0; j < 8; j++) zp[j] = zr[j];
    }
  }
}

// ------------- Reduce: sum bf16 partials (already [e][d]); emit kvt, Z ------
template<int NCH>
__global__ __launch_bounds__(256) void k_red(
    const ushort* __restrict__ part, const float* __restrict__ zpart,
    ushort* __restrict__ kvt, float* __restrict__ zout)
{
  const int bh = blockIdx.x >> 2;
  const int quad = blockIdx.x & 3;
  const int t = threadIdx.x;
  const long pbase = (long)bh * NCH * (DIM * DIM);

  // per bh: 16384 bf16 = 2048 uint4; per quad-block 512; per thread 2
#pragma unroll
  for (int i = 0; i < 2; i++) {
    int u4 = quad * 512 + t + i * 256;
    long off = pbase + (long)u4 * 8;
    float s[8] = {0.f, 0.f, 0.f, 0.f, 0.f, 0.f, 0.f, 0.f};
#pragma unroll
    for (int cc = 0; cc < NCH; cc++) {
      uint4 v = *(const uint4*)&part[off + (long)cc * (DIM * DIM)];
      unsigned ws_[4] = {v.x, v.y, v.z, v.w};
#pragma unroll
      for (int h = 0; h < 4; h++) {
        s[2 * h]     += bf2f((ushort)(ws_[h] & 0xFFFFu));
        s[2 * h + 1] += bf2f((ushort)(ws_[h] >> 16));
      }
    }
    unsigned o[4];
#pragma unroll
    for (int h = 0; h < 4; h++)
      o[h] = (unsigned)f2bf(s[2 * h]) | ((unsigned)f2bf(s[2 * h + 1]) << 16);
    *(uint4*)&kvt[(long)bh * (DIM * DIM) + (long)u4 * 8] =
        make_uint4(o[0], o[1], o[2], o[3]);
  }

  if (quad == 0 && t < DIM) {
    float s = 0.f;
#pragma unroll
    for (int cc = 0; cc < NCH; cc++) {
#pragma unroll
      for (int wv = 0; wv < 4; wv++)
        s += zpart[(((long)bh * NCH + cc) * 4 + wv) * DIM + t];
    }
    zout[(long)bh * DIM + t] = s;
  }
}

// --------- Kernel 2: out = (phi(Q) KV) / (phi(Q)·Z + eps) -------------------
#define QB 64
#define LDQ 136   // 128 + 8 pad

__global__ __launch_bounds__(256) void k2_fwd(
    const float* __restrict__ Qg, const ushort* __restrict__ kvt,
    const float* __restrict__ zg, float* __restrict__ outg)
{
  __shared__ ushort ql[QB * LDQ];
  __shared__ ushort kvl[DIM * LDQ];
  __shared__ float zl[DIM];
  __shared__ float dpart[4][QB];
  __shared__ float invd[QB];

  const int bid = blockIdx.x;
  const int bh = bid >> 5;
  const int q0 = (bid & 31) * QB;
  const int t = threadIdx.x;
  const int lane = t & 63;
  const int w = t >> 6;

  if (t < DIM) zl[t] = zg[(long)bh * DIM + t];

  // stage phi(Q) as bf16, row-major
  const float* Qp = Qg + ((long)bh * NQ + q0) * DIM;
#pragma unroll
  for (int i = 0; i < 8; i++) {
    int idx4 = t + i * 256;          // float4 chunk id
    int row = idx4 >> 5;
    int c4 = idx4 & 31;
    float4 v = *(const float4*)(Qp + (long)row * DIM + c4 * 4);
    ushort a = f2bf(phi_f(v.x)), b = f2bf(phi_f(v.y));
    ushort cq = f2bf(phi_f(v.z)), dq = f2bf(phi_f(v.w));
    uint2 pk;
    pk.x = (unsigned)a | ((unsigned)b << 16);
    pk.y = (unsigned)cq | ((unsigned)dq << 16);
    *(uint2*)&ql[row * LDQ + c4 * 4] = pk;
  }
  // stage KV^T (already bf16)
  const ushort* kp = kvt + (long)bh * (DIM * DIM);
#pragma unroll
  for (int i = 0; i < 8; i++) {
    int idx8 = t + i * 256;
    int row = idx8 >> 4;
    int c8 = idx8 & 15;
    uint4 vv = *(const uint4*)(kp + row * DIM + c8 * 8);
    *(uint4*)&kvl[row * LDQ + c8 * 8] = vv;
  }
  __syncthreads();

  // denominator per row
  {
    int row = t & (QB - 1);
    int q4 = t >> 6;
    float s = 0.f;
#pragma unroll
    for (int i = 0; i < 4; i++) {
      int d0 = q4 * 32 + i * 8;
      bf16x8 qv = *(const bf16x8*)&ql[row * LDQ + d0];
#pragma unroll
      for (int j = 0; j < 8; j++)
        s += bf2f((ushort)qv[j]) * zl[d0 + j];
    }
    dpart[q4][row] = s;
  }
  __syncthreads();
  if (t < QB) {
    float den = dpart[0][t] + dpart[1][t] + dpart[2][t] + dpart[3][t] + EPSV;
    invd[t] = 1.f / den;
  }
  __syncthreads();

  // numerator via MFMA: D[q][e] += A[q][d] * B[d][e]
  const int kk = (lane >> 4) * 8;
  const int qrow = w * 16 + (lane & 15);
  f32x4 acc[8];
#pragma unroll
  for (int et = 0; et < 8; et++) acc[et] = (f32x4){0.f, 0.f, 0.f, 0.f};

#pragma unroll
  for (int d0 = 0; d0 < DIM; d0 += 32) {
    bf16x8 afr = *(const bf16x8*)&ql[qrow * LDQ + d0 + kk];
#pragma unroll
    for (int et = 0; et < 8; et++) {
      int e = et * 16 + (lane & 15);
      bf16x8 bfr = *(const bf16x8*)&kvl[e * LDQ + d0 + kk];
      acc[et] = __builtin_amdgcn_mfma_f32_16x16x32_bf16(afr, bfr, acc[et], 0, 0, 0);
    }
  }

  // epilogue: scale by 1/den, store f32
  float* op = outg + ((long)bh * NQ + q0) * DIM;
#pragma unroll
  for (int et = 0; et < 8; et++) {
    int e = et * 16 + (lane & 15);
    int r0 = w * 16 + (lane >> 4) * 4;
#pragma unroll
    for (int r = 0; r < 4; r++) {
      float val = acc[et][r] * invd[r0 + r];
      op[(long)(r0 + r) * DIM + e] = val;
    }
  }
}

extern "C" void kernel_launch(void* const* d_in, const int* in_sizes, int n_in,
                              void* d_out, int out_size, void* d_ws, size_t ws_size,
                              hipStream_t stream) {
  const float* Q  = (const float*)d_in[0];
  const float* Km = (const float*)d_in[1];
  const float* Vm = (const float*)d_in[2];
  float* out = (float*)d_out;

  char* ws = (char*)d_ws;
  ushort* kvt = (ushort*)ws;                                    // 64*16384*2 = 2 MB
  float* zred = (float*)(ws + (size_t)BH * DIM * DIM * 2);      // 32 KB
  size_t fixed = (size_t)BH * DIM * DIM * 2 + (size_t)BH * DIM * 4;

  int nch = 16;
  while (nch > 1) {
    size_t need = fixed + (size_t)BH * nch * DIM * DIM * 2
                + (size_t)BH * nch * 4 * DIM * 4;
    if (need <= ws_size) break;
    nch >>= 1;
  }
  ushort* partb = (ushort*)(ws + fixed);
  float* zpart = (float*)(ws + fixed + (size_t)BH * nch * DIM * DIM * 2);
  int ck = NKV / nch;

  k1_kv<<<BH * nch, 512, 0, stream>>>(Km, Vm, partb, zpart, nch, ck);

  dim3 rg(BH * 4);
  switch (nch) {
    case 16: k_red<16><<<rg, 256, 0, stream>>>(partb, zpart, kvt, zred); break;
    case 8:  k_red<8> <<<rg, 256, 0, stream>>>(partb, zpart, kvt, zred); break;
    case 4:  k_red<4> <<<rg, 256, 0, stream>>>(partb, zpart, kvt, zred); break;
    case 2:  k_red<2> <<<rg, 256, 0, stream>>>(partb, zpart, kvt, zred); break;
    default: k_red<1> <<<rg, 256, 0, stream>>>(partb, zpart, kvt, zred); break;
  }

  k2_fwd<<<BH * 32, 256, 0, stream>>>(Q, kvt, zred, out);
}